// Round 20
// baseline (33.091 us; speedup 1.0000x reference)
//
#include <hip/hip_runtime.h>
#include <math.h>

#define NIMG 24        // B*C = 8*3
#define H    256
#define W    256
#define NPIX (H * W)
#define CPB  16                   // columns per block
#define GRPS (W / CPB)            // 16
#define NBLK (NIMG * GRPS)        // 384
#define LDP  17                   // padded LDS row stride (floats)
#define BIGI 1000000

// ---------------------------------------------------------------------------
// SINGLE main kernel (r20): K1 merged into K2 with NO redundant EDT and NO
// global f round-trip. r19 insight: the row EDT only needs the per-row
// 256-bit class-change mask (32 B) — so one block builds masks for ALL 256
// rows of its image in LDS (8 KB) from one image read (L2-resident via
// XCD-aware img mapping; unlike r14 which redundantly recomputed the FULL
// EDT 32x and died on VALU, the expensive per-pixel walk runs exactly once
// per pixel here). r15-r19 lesson: per-node cost ~4-6us dominates short
// pipelines — this cuts the dependency chain to main + tiny finalize.
//
// Phase 1: 16 chunk-tasks/thread -> change bits (+ sign bits for own cols)
//          into LDS; whole-image scan gives the EXACT empty flag.
// Phase 2: thread t = row t: initial last/next via masked clz/ctz over the
//          4 mask words, then 16-px incremental walk (r19-validated,
//          bit-exact integer arithmetic; cap -> +-1e6f, r13-validated).
// Phase B: r17-validated window-bounded exact min-plus (minimizer satisfies
//          |i-k| <= g[i]; all finite terms exact fp32 ints -> bitwise equal
//          to reference), pred prefetch, fixed-order double reduce ->
//          partials[bid] (plain store; no atomics/fences — falsified 3x).
// ---------------------------------------------------------------------------
__global__ __launch_bounds__(256)
void boundary_main_kernel(const int* __restrict__ tgt,
                          const float* __restrict__ pred,
                          double* __restrict__ partials) {
    const int bid = blockIdx.x;
    const int xcd = bid & 7;
    const int k   = bid >> 3;            // 0..47
    const int img = xcd * 3 + (k % 3);   // XCD-local image (L2 locality)
    const int grp = k / 3;               // 0..15
    const int j0  = grp << 4;
    const int t   = threadIdx.x;
    const int lane = t & 63;
    const int wid  = t >> 6;
    const int ibase = img << 16;

    __shared__ unsigned long long m[H][4];   // 8 KB: per-row change masks
    __shared__ unsigned short sgnb[H];       // own-16-col sign bits per row
    __shared__ float sf[H][LDP];             // 17.4 KB: f slice
    __shared__ double wsum[4];
    __shared__ int nonempty;
    if (t == 0) nonempty = 0;
    __syncthreads();

    // ---------------- phase 1: build change masks (whole image) ----------
    int anynz = 0;
#pragma unroll 2
    for (int s = 0; s < 16; ++s) {
        const int task = (s << 8) + t;       // 0..4095
        const int row  = task >> 4;
        const int ck   = task & 15;
        const int base = ibase + (row << 8) + (ck << 4);
        const int4* rp = (const int4*)(tgt + base);
        const int4 v0 = rp[0], v1 = rp[1], v2 = rp[2], v3 = rp[3];
        int va[16];
        *(int4*)&va[0]  = v0;  *(int4*)&va[4]  = v1;
        *(int4*)&va[8]  = v2;  *(int4*)&va[12] = v3;
        const int prevv = ck ? tgt[base - 1] : 0;

        unsigned int bits = 0, sbits = 0;
        bool pc = (prevv != 0);
#pragma unroll
        for (int i = 0; i < 16; ++i) {
            const bool c = (va[i] != 0);
            if (c != pc) bits |= (1u << i);
            if (c) sbits |= (1u << i);
            pc = c;
        }
        if (ck == 0) bits &= ~1u;            // col 0 has no predecessor
        anynz |= sbits;
        ((unsigned short*)m)[task] = (unsigned short)bits;  // = m[row][ck]
        if (ck == grp) sgnb[row] = (unsigned short)sbits;
    }
    if (anynz) nonempty = 1;                 // benign race, all write 1
    __syncthreads();

    // ---------------- phase 2: row t -> f values for own 16 cols ----------
    {
        const int row = t;
        const unsigned long long M0 = m[row][0], M1 = m[row][1];
        const unsigned long long M2 = m[row][2], M3 = m[row][3];
        const int wlo = grp >> 2;
        const int blo = (grp & 3) << 4;
        const int bhi = blo + 16;

        // last change at position < j0 (else -BIGI)
        const unsigned long long pm  = blo ? ((1ULL << blo) - 1ULL) : 0ULL;
        const unsigned long long lm0 = (wlo > 0) ? ~0ULL : pm;
        const unsigned long long lm1 = (wlo > 1) ? ~0ULL : ((wlo == 1) ? pm : 0ULL);
        const unsigned long long lm2 = (wlo > 2) ? ~0ULL : ((wlo == 2) ? pm : 0ULL);
        const unsigned long long lm3 = (wlo == 3) ? pm : 0ULL;
        int last = -BIGI;
        {
            unsigned long long x;
            x = M0 & lm0; if (x) last = 63 - __builtin_clzll(x);
            x = M1 & lm1; if (x) last = 127 - __builtin_clzll(x);
            x = M2 & lm2; if (x) last = 191 - __builtin_clzll(x);
            x = M3 & lm3; if (x) last = 255 - __builtin_clzll(x);
        }
        // first change at position >= j0+16 (else BIGI)
        const unsigned long long sm  = (bhi == 64) ? 0ULL : ~((1ULL << bhi) - 1ULL);
        const unsigned long long hm0 = (wlo == 0) ? sm : 0ULL;
        const unsigned long long hm1 = (wlo < 1) ? ~0ULL : ((wlo == 1) ? sm : 0ULL);
        const unsigned long long hm2 = (wlo < 2) ? ~0ULL : ((wlo == 2) ? sm : 0ULL);
        const unsigned long long hm3 = (wlo < 3) ? ~0ULL : sm;
        int nxt_hi = BIGI;
        {
            unsigned long long x;
            x = M3 & hm3; if (x) nxt_hi = 192 + __builtin_ctzll(x);
            x = M2 & hm2; if (x) nxt_hi = 128 + __builtin_ctzll(x);
            x = M1 & hm1; if (x) nxt_hi =  64 + __builtin_ctzll(x);
            x = M0 & hm0; if (x) nxt_hi =       __builtin_ctzll(x);
        }

        const unsigned long long Mw =
            (wlo == 0) ? M0 : (wlo == 1) ? M1 : (wlo == 2) ? M2 : M3;
        unsigned int rem = (unsigned int)((Mw >> blo) & 0xFFFFULL);
        const unsigned int sb = sgnb[row];
#pragma unroll
        for (int i = 0; i < 16; ++i) {
            const int j = j0 + i;
            if (rem & 1u) last = j;          // change AT j -> run starts here
            rem >>= 1;
            const int n  = rem ? (j + 1 + __builtin_ctz(rem)) : nxt_hi;
            const int dp = j - last + 1;
            const int dn = n - j;
            const int g  = dp < dn ? dp : dn;
            const float gf = (g < BIGI) ? (float)g : 1.0e6f;
            sf[row][i] = ((sb >> i) & 1u) ? gf : -gf;
        }
    }
    __syncthreads();
    const int flag = nonempty;               // exact: mask.sum() != 0

    // ---------------- phase B: window-bounded exact min-plus --------------
    const int c  = t & 15;                   // own column within tile
    const int r0 = (t >> 4) << 4;            // own 16-row band
    float pf[16];
#pragma unroll
    for (int ii = 0; ii < 16; ++ii)
        pf[ii] = pred[ibase + ((r0 + ii) << 8) + j0 + c];

    double acc = 0.0;
#pragma unroll 4
    for (int ii = 0; ii < 16; ++ii) {
        const int i = r0 + ii;
        const float fv = sf[i][c];
        const bool  m2 = fv > 0.0f;          // sign(f) = pixel polarity
        const float sgn = m2 ? 1.0f : -1.0f;
        const float gi = fabsf(fv);
        const int  gii = (int)gi;
        int lo = i - gii; lo = lo > 0 ? lo : 0;
        int hi = i + gii; hi = hi < (H - 1) ? hi : (H - 1);

        float dm = 3.0e38f;
        float dk = (float)(i - lo);
        for (int kk = lo; kk <= hi; ++kk) {
            const float g = fmaxf(sgn * sf[kk][c], 0.0f);  // needed polarity
            dm = fminf(dm, g * g + dk * dk);
            dk -= 1.0f;
        }

        float d = m2 ? sqrtf(dm) : -sqrtf(dm);
        if (!flag) d = 0.0f;
        const float sig = 1.0f / (1.0f + expf(-pf[ii]));
        acc += (double)sig * (double)d;
    }

    // wave reduce (double, fixed order), 4 wave sums -> plain-store partial
#pragma unroll
    for (int off = 32; off > 0; off >>= 1) acc += __shfl_down(acc, off, 64);
    if (lane == 0) wsum[wid] = acc;
    __syncthreads();
    if (t == 0) partials[bid] = (wsum[0] + wsum[1]) + (wsum[2] + wsum[3]);
}

// ---------------------------------------------------------------------------
// Finalize: deterministic fixed-order sum of 384 partials -> mean -> fp32.
// Plain write to out[0] (poison-safe, no atomics).
// ---------------------------------------------------------------------------
__global__ void finalize_kernel(const double* __restrict__ partials,
                                float* __restrict__ out) {
    const int t = threadIdx.x;               // 64 threads
    double a = 0.0;
#pragma unroll
    for (int s = 0; s < NBLK / 64; ++s) a += partials[t + (s << 6)];
#pragma unroll
    for (int off = 32; off > 0; off >>= 1) a += __shfl_down(a, off, 64);
    if (t == 0) out[0] = (float)(a / (double)(NIMG * NPIX));
}

extern "C" void kernel_launch(void* const* d_in, const int* in_sizes, int n_in,
                              void* d_out, int out_size, void* d_ws, size_t ws_size,
                              hipStream_t stream) {
    const float* pred = (const float*)d_in[0];
    const int*   tgt  = (const int*)d_in[1];
    float* out = (float*)d_out;

    double* partials = (double*)d_ws;        // 384 * 8 B

    boundary_main_kernel<<<NBLK, 256, 0, stream>>>(tgt, pred, partials);
    finalize_kernel<<<1, 64, 0, stream>>>(partials, out);
}

// Round 22
// 24.282 us; speedup vs baseline: 1.3628x; 1.3628x over previous
//
#include <hip/hip_runtime.h>
#include <math.h>

#define NIMG 24        // B*C = 8*3
#define H    256
#define W    256
#define NPIX (H * W)
#define NROWS (NIMG * H)          // 6144
#define CPB  16                   // columns per K2 tile
#define NBLK2 (NIMG * (W / CPB))  // 384
#define LDP2 17                   // padded LDS row stride (floats)
#define BIGI 1000000
#define CAPS 1024                 // int16 sentinel for capped g (=1e6)

// ---------------------------------------------------------------------------
// r22: CORRECTNESS REVERT. r21 exposed a flaky cross-XCD race in the
// K1-plain-store-zero + K2-atomicAdd finalize (passed r16-r19 by luck,
// failed post-timing revalidation in r21: plain store dirty in one XCD's
// L2 mixed with agent-scope RMWs on the same line is not reliably ordered
// across node boundaries under graph replay). This pipeline uses PLAIN
// STORES ONLY across node boundaries (the one discipline with zero flakes
// all session): K1 -> f, K2 -> partials, K3 finalize -> out.
//
// K1 (r17-validated): 384 blocks x 256 thr, hoisted row loads, ballot O(1)
// row EDT (r11-validated bit-exact), int16 f (r13-validated encode).
// ---------------------------------------------------------------------------
__global__ __launch_bounds__(256)
void edt_rows_kernel(const int* __restrict__ tgt,
                     short* __restrict__ f) {
    const int lane = threadIdx.x & 63;
    const int wid  = threadIdx.x >> 6;        // 0..3
    const int gw   = blockIdx.x * 4 + wid;    // 0..1535
    const int c0   = lane << 2;

    int4 tvs[4];
#pragma unroll
    for (int s = 0; s < 4; ++s)
        tvs[s] = ((const int4*)(tgt + (((gw << 2) + s) << 8)))[lane];

#pragma unroll
    for (int s = 0; s < 4; ++s) {
        const int row = (gw << 2) + s;
        const int4 tv = tvs[s];

        const int prevw = __shfl_up(tv.w, 1, 64);
        const bool ch0 = (lane > 0) && ((tv.x != 0) != (prevw != 0));
        const bool ch1 = (tv.y != 0) != (tv.x != 0);
        const bool ch2 = (tv.z != 0) != (tv.y != 0);
        const bool ch3 = (tv.w != 0) != (tv.z != 0);

        const int a0 = ch0 ? c0     : -BIGI;
        const int a1 = ch1 ? c0 + 1 : a0;
        const int a2 = ch2 ? c0 + 2 : a1;
        const int a3 = ch3 ? c0 + 3 : a2;     // lane's last change (or -BIGI)
        const int rb3 = ch3 ? c0 + 3 : BIGI;
        const int rb2 = ch2 ? c0 + 2 : rb3;
        const int rb1 = ch1 ? c0 + 1 : rb2;
        const int rb0 = ch0 ? c0     : rb1;   // lane's first change (or BIGI)

        const unsigned long long mask = __ballot(ch0 | ch1 | ch2 | ch3);
        const unsigned long long lowm = mask & ((1ULL << lane) - 1ULL);
        const unsigned long long him  = (lane < 63) ? (mask >> (lane + 1)) : 0ULL;

        const int plane = 63 - __builtin_clzll(lowm | 1ULL);
        const int sh_a  = __shfl(a3, plane & 63, 64);
        const int ex    = (lowm != 0ULL) ? sh_a : -BIGI;   // last change < c0

        const int qlane = lane + 1 +
            (int)__builtin_ctzll(him | 0x8000000000000000ULL);
        const int sh_r  = __shfl(rb0, qlane & 63, 64);
        const int exr   = (him != 0ULL) ? sh_r : BIGI;     // first change > c3

        const int s0 = (ex > a0) ? ex : a0;
        const int s1 = (ex > a1) ? ex : a1;
        const int s2 = (ex > a2) ? ex : a2;
        const int s3 = (ex > a3) ? ex : a3;
        const int n0 = (rb1 < exr) ? rb1 : exr;
        const int n1 = (rb2 < exr) ? rb2 : exr;
        const int n2 = (rb3 < exr) ? rb3 : exr;
        const int n3 = exr;

        auto gcalc = [](int c, int ss, int nn) -> int {
            int dp = c - ss + 1;
            int dn = nn - c;
            int g = dp < dn ? dp : dn;
            return (g < BIGI) ? g : CAPS;     // encode cap as sentinel
        };
        const int g0 = gcalc(c0,     s0, n0);
        const int g1 = gcalc(c0 + 1, s1, n1);
        const int g2 = gcalc(c0 + 2, s2, n2);
        const int g3 = gcalc(c0 + 3, s3, n3);

        short4 o;
        o.x = (short)((tv.x != 0) ? g0 : -g0);
        o.y = (short)((tv.y != 0) ? g1 : -g1);
        o.z = (short)((tv.z != 0) ? g2 : -g2);
        o.w = (short)((tv.w != 0) ? g3 : -g3);
        ((short4*)(f + (row << 8)))[lane] = o;
    }
}

// ---------------------------------------------------------------------------
// K2 (r17-validated math): 384 blocks x 512 thr, tile = (img, 16-col
// group). int16 decode (sentinel +-1024 -> +-1e6f, r13-validated),
// empty-mask flag from cap markers, pred prefetch, window-bounded exact
// min-plus (minimizer satisfies |i-k| <= g[i] since k=i gives g[i]^2; all
// finite terms exact fp32 ints -> bitwise equal to reference), 8-wave
// fixed-order double reduce -> partials[bid] via PLAIN STORE.
// ---------------------------------------------------------------------------
__global__ __launch_bounds__(512)
void edt_cols_kernel(const short* __restrict__ f,
                     const float* __restrict__ pred,
                     double* __restrict__ partials) {
    const int bid  = blockIdx.x;          // img*16 + grp
    const int img  = bid >> 4;
    const int j0   = (bid & 15) << 4;
    const int t    = threadIdx.x;
    const int lane = t & 63;
    const int wid  = t >> 6;

    __shared__ float sf[H][LDP2];
    __shared__ double wsum[8];
    __shared__ int nonempty;
    if (t == 0) nonempty = 0;
    __syncthreads();

    {
        const int row = t >> 1;
        const int q   = (t & 1) << 3;
        const int4 rv = *(const int4*)(f + (img << 16) + (row << 8) + j0 + q);
        const short* sv = (const short*)&rv;
        bool ne = false;
#pragma unroll
        for (int j = 0; j < 8; ++j) {
            const int v = sv[j];
            ne = ne || (v != -CAPS);
            float g = (float)v;
            if (v == CAPS)  g =  1.0e6f;
            if (v == -CAPS) g = -1.0e6f;
            sf[row][q + j] = g;
        }
        if (ne) nonempty = 1;             // benign race, all write 1
    }

    const int c  = t & 15;
    const int r0 = (t >> 4) << 3;
    float pf[8];
#pragma unroll
    for (int ii = 0; ii < 8; ++ii)
        pf[ii] = pred[(img << 16) + ((r0 + ii) << 8) + j0 + c];

    __syncthreads();
    const int flag = nonempty;            // exact: mask.sum() != 0

    double acc = 0.0;
#pragma unroll
    for (int ii = 0; ii < 8; ++ii) {
        const int i = r0 + ii;
        const float fv = sf[i][c];
        const bool  m  = fv > 0.0f;       // sign(f) = pixel polarity
        const float sgn = m ? 1.0f : -1.0f;
        const float gi = fabsf(fv);
        const int  gii = (int)gi;
        int lo = i - gii; lo = lo > 0 ? lo : 0;
        int hi = i + gii; hi = hi < (H - 1) ? hi : (H - 1);

        float dm = 3.0e38f;
        float dk = (float)(i - lo);
        for (int k = lo; k <= hi; ++k) {
            const float g = fmaxf(sgn * sf[k][c], 0.0f);  // needed polarity
            dm = fminf(dm, g * g + dk * dk);
            dk -= 1.0f;
        }

        float d = m ? sqrtf(dm) : -sqrtf(dm);
        if (!flag) d = 0.0f;
        const float sig = 1.0f / (1.0f + expf(-pf[ii]));
        acc += (double)sig * (double)d;
    }

#pragma unroll
    for (int off = 32; off > 0; off >>= 1) acc += __shfl_down(acc, off, 64);
    if (lane == 0) wsum[wid] = acc;
    __syncthreads();
    if (t == 0) {
        double s = 0.0;
#pragma unroll
        for (int w = 0; w < 8; ++w) s += wsum[w];
        partials[bid] = s;                // plain store, no atomics
    }
}

// ---------------------------------------------------------------------------
// K3: deterministic fixed-order sum of 384 partials -> mean -> fp32.
// Plain write to out[0]. No atomics anywhere in the pipeline.
// ---------------------------------------------------------------------------
__global__ void finalize_kernel(const double* __restrict__ partials,
                                float* __restrict__ out) {
    const int t = threadIdx.x;            // 64 threads
    double a = 0.0;
#pragma unroll
    for (int s = 0; s < NBLK2 / 64; ++s) a += partials[t + (s << 6)];
#pragma unroll
    for (int off = 32; off > 0; off >>= 1) a += __shfl_down(a, off, 64);
    if (t == 0) out[0] = (float)(a / (double)(NIMG * NPIX));
}

extern "C" void kernel_launch(void* const* d_in, const int* in_sizes, int n_in,
                              void* d_out, int out_size, void* d_ws, size_t ws_size,
                              hipStream_t stream) {
    const float* pred = (const float*)d_in[0];
    const int*   tgt  = (const int*)d_in[1];
    float* out = (float*)d_out;

    char* ws = (char*)d_ws;
    const size_t fbytes = (size_t)NIMG * NPIX * sizeof(short);   // 3,145,728 B
    short*  fbuf     = (short*)(ws);
    double* partials = (double*)(ws + fbytes);                   // 384 * 8 B

    edt_rows_kernel<<<384, 256, 0, stream>>>(tgt, fbuf);
    edt_cols_kernel<<<NBLK2, 512, 0, stream>>>(fbuf, pred, partials);
    finalize_kernel<<<1, 64, 0, stream>>>(partials, out);
}